// Round 5
// baseline (4103.581 us; speedup 1.0000x reference)
//
#include <hip/hip_runtime.h>
#include <math.h>

// Problem constants
#define BDIM 4096
#define TLEN 48
#define FEAT 35
#define HID 1024
#define H4 4096
#define KTOT 1152      // 1024 (hh) + 128 (ih, 70 real + 58 zero pad)
#define KIH2 128

#define BH ((size_t)BDIM * HID)

typedef unsigned short u16;
typedef __bf16 bf16x8 __attribute__((ext_vector_type(8)));
typedef float f32x4 __attribute__((ext_vector_type(4)));
typedef u16 u16x8 __attribute__((ext_vector_type(8)));

__device__ __forceinline__ float b2f(u16 u) {
    union { float f; unsigned i; } v; v.i = ((unsigned)u) << 16; return v.f;
}
__device__ __forceinline__ u16 f2b(float f) {
    union { float f; unsigned i; } v; v.f = f;
    unsigned r = v.i + 0x7FFF + ((v.i >> 16) & 1);
    return (u16)(r >> 16);
}
__device__ __forceinline__ float sigf(float x) { return __builtin_amdgcn_rcpf(1.f + __expf(-x)); }
__device__ __forceinline__ float tanh_fast(float x) { return 1.f - 2.f * __builtin_amdgcn_rcpf(1.f + __expf(2.f * x)); }

// ---------------- prep kernels ----------------
// Combined bf16 weight matrix W[4096][1152], rows reordered:
// orig n = g*HID + j  ->  new n = (j>>5)*128 + g*32 + (j&31)
__global__ __launch_bounds__(256) void prep_w(const float* __restrict__ W_hh, const float* __restrict__ W_ih,
                                              u16* __restrict__ W) {
    int newn = blockIdx.x;
    int nbk = newn >> 7, rem = newn & 127, g = rem >> 5, jl = rem & 31;
    int orig = g * HID + nbk * 32 + jl;
    u16* dst = W + (size_t)newn * KTOT;
    const float* src = W_hh + (size_t)orig * HID;
    #pragma unroll
    for (int it = 0; it < 4; ++it) { int k = it * 256 + threadIdx.x; dst[k] = f2b(src[k]); }
    int k2 = threadIdx.x;
    if (k2 < KIH2) dst[HID + k2] = (k2 < 2 * FEAT) ? f2b(W_ih[(size_t)orig * (2 * FEAT) + k2]) : (u16)0;
}

__global__ __launch_bounds__(256) void prep_bias(const float* __restrict__ b_ih, const float* __restrict__ b_hh,
                                                 float* __restrict__ bias_r) {
    int newn = blockIdx.x * 256 + threadIdx.x;
    int nbk = newn >> 7, rem = newn & 127, g = rem >> 5, jl = rem & 31;
    int orig = g * HID + nbk * 32 + jl;
    bias_r[newn] = b_ih[orig] + b_hh[orig];
}

// tdWtb[j][f] bf16, [1024][64], f>=35 zero.  td_W is [HID][FEAT] row-major already.
__global__ __launch_bounds__(256) void prep_tdwtb(const float* __restrict__ td_W, u16* __restrict__ tdWtb) {
    int idx = blockIdx.x * 256 + threadIdx.x;   // 1024*64 = 256*256
    int row = idx >> 6, f = idx & 63;
    tdWtb[idx] = (f < FEAT) ? f2b(td_W[(size_t)row * FEAT + f]) : (u16)0;
}

// regWb[f][k] bf16, [48][1024], f>=35 zero.  reg_W is [FEAT][HID] row-major.
__global__ __launch_bounds__(256) void prep_regwb(const float* __restrict__ reg_W, u16* __restrict__ regWb) {
    int idx = blockIdx.x * 256 + threadIdx.x;   // 48*1024 = 192*256
    int row = idx >> 10, col = idx & 1023;
    regWb[idx] = (row < FEAT) ? f2b(reg_W[(size_t)row * HID + col]) : (u16)0;
}

// ---------------- stepR: regression + x_c + loss + gamma(t+1) ----------------
__global__ __launch_bounds__(256) void stepR(const float* __restrict__ values, const float* __restrict__ masks,
                                             const float* __restrict__ deltas, const u16* __restrict__ tdWtb,
                                             const float* __restrict__ td_b, const u16* __restrict__ regWb,
                                             const float* __restrict__ reg_b, u16* __restrict__ X,
                                             u16* __restrict__ gbuf, float* __restrict__ imput,
                                             float* __restrict__ xnum_part, float* __restrict__ xden_part,
                                             int t, int gflag) {
    __shared__ u16 d_sh[16 * 64];          // bf16 d(t+1), 16B-chunk XOR swizzled per row
    __shared__ float x_sh[16 * 35], m_sh[16 * 35];
    __shared__ float xhp[4][16][49];       // per-wave regression partials (padded)
    __shared__ float redbuf[8];

    int tid = threadIdx.x;
    int wave = tid >> 6, lane = tid & 63;
    int cl = lane & 15, quad = lane >> 4;
    int b0 = blockIdx.x * 16;

    for (int i = tid; i < 16 * 35; i += 256) {
        int b = i / 35, f = i - b * 35;
        size_t g = ((size_t)(b0 + b) * TLEN + t) * FEAT + f;
        x_sh[i] = values[g];
        m_sh[i] = masks[g];
    }
    if (gflag && tid < 128) {
        int b = tid >> 3, cch = tid & 7;
        const float* drow = deltas + ((size_t)(b0 + b) * TLEN + (t + 1)) * FEAT;
        u16x8 tv;
        #pragma unroll
        for (int k = 0; k < 8; ++k) {
            int f = cch * 8 + k;
            tv[k] = (f < FEAT) ? f2b(drow[f]) : (u16)0;
        }
        int csw = cch ^ (b & 7);
        *(u16x8*)(d_sh + b * 64 + csw * 8) = tv;
    }
    __syncthreads();

    // ---- regression MFMA (K split: wave covers K [wave*256, wave*256+256)) ----
    f32x4 racc[3];
    #pragma unroll
    for (int nt = 0; nt < 3; ++nt) racc[nt] = (f32x4){0.f, 0.f, 0.f, 0.f};
    const u16* xrow = X + (size_t)(b0 + cl) * KTOT + wave * 256;
    #pragma unroll
    for (int ks = 0; ks < 8; ++ks) {
        bf16x8 av = *(const bf16x8*)(xrow + ks * 32 + quad * 8);
        #pragma unroll
        for (int nt = 0; nt < 3; ++nt) {
            bf16x8 bv = *(const bf16x8*)(regWb + (size_t)(nt * 16 + cl) * 1024 + wave * 256 + ks * 32 + quad * 8);
            racc[nt] = __builtin_amdgcn_mfma_f32_16x16x32_bf16(av, bv, racc[nt], 0, 0, 0);
        }
    }
    #pragma unroll
    for (int nt = 0; nt < 3; ++nt)
        #pragma unroll
        for (int r = 0; r < 4; ++r)
            xhp[wave][quad * 4 + r][nt * 16 + cl] = racc[nt][r];

    // ---- gamma MFMA: wave covers j-tiles [wave*16, wave*16+16) ----
    if (gflag) {
        int swc0 = quad ^ (cl & 7);
        int swc1 = (4 + quad) ^ (cl & 7);
        bf16x8 a0 = *(const bf16x8*)(d_sh + cl * 64 + swc0 * 8);
        bf16x8 a1 = *(const bf16x8*)(d_sh + cl * 64 + swc1 * 8);
        #pragma unroll 4
        for (int jt2 = 0; jt2 < 16; ++jt2) {
            int jt = wave * 16 + jt2;
            const u16* tw = tdWtb + (size_t)(jt * 16 + cl) * 64;
            bf16x8 b0v = *(const bf16x8*)(tw + quad * 8);
            bf16x8 b1v = *(const bf16x8*)(tw + 32 + quad * 8);
            f32x4 g4 = (f32x4){0.f, 0.f, 0.f, 0.f};
            g4 = __builtin_amdgcn_mfma_f32_16x16x32_bf16(a0, b0v, g4, 0, 0, 0);
            g4 = __builtin_amdgcn_mfma_f32_16x16x32_bf16(a1, b1v, g4, 0, 0, 0);
            float4 tb = *(const float4*)(td_b + jt * 16 + quad * 4);
            float tbv[4] = {tb.x, tb.y, tb.z, tb.w};
            #pragma unroll
            for (int r = 0; r < 4; ++r) {
                u16 gam = f2b(__expf(-fmaxf(g4[r] + tbv[r], 0.f)));
                gbuf[(size_t)(b0 + quad * 4 + r) * HID + jt * 16 + cl] = gam;
            }
        }
    }
    __syncthreads();

    // ---- epilogue: x_c, imputations, X tail, loss partials ----
    float lossN = 0.f, lossD = 0.f;
    for (int i = tid; i < 16 * 35; i += 256) {
        int b = i / 35, f = i - b * 35;
        float xh = xhp[0][b][f] + xhp[1][b][f] + xhp[2][b][f] + xhp[3][b][f] + reg_b[f];
        float xv = x_sh[i], mv = m_sh[i];
        float xc = mv * xv + (1.f - mv) * xh;
        imput[((size_t)(b0 + b) * TLEN + t) * FEAT + f] = xc;
        u16* Xr = X + (size_t)(b0 + b) * KTOT;
        Xr[HID + f] = f2b(xc);
        Xr[HID + FEAT + f] = f2b(mv);
        lossN += fabsf(xv - xh) * mv;
        lossD += mv;
    }
    for (int i = tid; i < 16 * 58; i += 256) {
        int b = i / 58, k = i - b * 58;
        X[(size_t)(b0 + b) * KTOT + HID + 2 * FEAT + k] = 0;
    }
    #pragma unroll
    for (int off = 32; off; off >>= 1) {
        lossN += __shfl_down(lossN, off);
        lossD += __shfl_down(lossD, off);
    }
    if (lane == 0) { redbuf[wave] = lossN; redbuf[4 + wave] = lossD; }
    __syncthreads();
    if (tid == 0) {
        xnum_part[t * 256 + blockIdx.x] = redbuf[0] + redbuf[1] + redbuf[2] + redbuf[3];
        xden_part[t * 256 + blockIdx.x] = redbuf[4] + redbuf[5] + redbuf[6] + redbuf[7];
    }
}

// ---------------- stepB: bf16 MFMA gates GEMM + fused LSTM cell + decay for t+1 ----------------
// 1D grid of 1024 blocks, XCD-aware decode (id%8 = XCD heuristic):
//   xcd = lid&7 owns nb in [xcd*4, xcd*4+4) x all 32 mb  ->  per-XCD L2 working set:
//   W slice 1.18 MB (resident across all 48 steps) + streaming X rows shared by the
//   4 concurrent same-mb blocks. Cuts per-step L2-miss staging traffic ~6x.
__global__ __launch_bounds__(256) void stepB(const u16* __restrict__ X, const u16* __restrict__ W,
                                             const float* __restrict__ bias_r, const u16* __restrict__ gbuf,
                                             float* __restrict__ c, u16* __restrict__ Xn,
                                             u16* __restrict__ h, int last) {
    __shared__ u16 As[128 * 64];
    __shared__ u16 Bs[128 * 64];
    int lid = blockIdx.x;
    int nb = (lid & 7) * 4 + ((lid >> 3) & 3);
    int mb = lid >> 5;
    int tid = threadIdx.x;
    int wave = tid >> 6, lane = tid & 63;
    int lrow = lane >> 3;            // 0..7 row within 8-row staging group
    int gchunk = (lane & 7) ^ lrow;  // swizzled global 16B-chunk to fetch
    int cl = lane & 15, quad = lane >> 4;

    f32x4 acc[2][8];
    #pragma unroll
    for (int mi = 0; mi < 2; ++mi)
        #pragma unroll
        for (int ni = 0; ni < 8; ++ni) acc[mi][ni] = (f32x4){0.f, 0.f, 0.f, 0.f};

    for (int kt = 0; kt < KTOT / 64; ++kt) {
        __syncthreads();
        #pragma unroll
        for (int it = 0; it < 4; ++it) {
            int rl = wave * 32 + it * 8;
            const u16* ga = X + (size_t)(mb * 128 + rl + lrow) * KTOT + kt * 64 + gchunk * 8;
            __builtin_amdgcn_global_load_lds((const __attribute__((address_space(1))) void*)ga,
                                             (__attribute__((address_space(3))) void*)(As + rl * 64),
                                             16, 0, 0);
            const u16* gb = W + (size_t)(nb * 128 + rl + lrow) * KTOT + kt * 64 + gchunk * 8;
            __builtin_amdgcn_global_load_lds((const __attribute__((address_space(1))) void*)gb,
                                             (__attribute__((address_space(3))) void*)(Bs + rl * 64),
                                             16, 0, 0);
        }
        __syncthreads();

        #pragma unroll
        for (int s = 0; s < 2; ++s) {
            int cs = (((4 * s + quad) ^ (cl & 7)) << 3);
            bf16x8 a0 = *(const bf16x8*)(As + (wave * 32 + cl) * 64 + cs);
            bf16x8 a1 = *(const bf16x8*)(As + (wave * 32 + 16 + cl) * 64 + cs);
            bf16x8 bv[8];
            #pragma unroll
            for (int ni = 0; ni < 8; ++ni) bv[ni] = *(const bf16x8*)(Bs + (ni * 16 + cl) * 64 + cs);
            #pragma unroll
            for (int ni = 0; ni < 8; ++ni) {
                acc[0][ni] = __builtin_amdgcn_mfma_f32_16x16x32_bf16(a0, bv[ni], acc[0][ni], 0, 0, 0);
                acc[1][ni] = __builtin_amdgcn_mfma_f32_16x16x32_bf16(a1, bv[ni], acc[1][ni], 0, 0, 0);
            }
        }
    }

    // fused LSTM epilogue; for t<47 write X_hdec(t+1) = h*gamma(t+1), for t=47 write h.
    #pragma unroll
    for (int mi = 0; mi < 2; ++mi) {
        #pragma unroll
        for (int r = 0; r < 4; ++r) {
            int b = mb * 128 + wave * 32 + mi * 16 + quad * 4 + r;
            #pragma unroll
            for (int jh = 0; jh < 2; ++jh) {
                int jl = jh * 16 + cl;
                int j = nb * 32 + jl;
                float iv = acc[mi][jh + 0][r] + bias_r[nb * 128 + jl];
                float fv = acc[mi][jh + 2][r] + bias_r[nb * 128 + 32 + jl];
                float gg = acc[mi][jh + 4][r] + bias_r[nb * 128 + 64 + jl];
                float ov = acc[mi][jh + 6][r] + bias_r[nb * 128 + 96 + jl];
                iv = sigf(iv); fv = sigf(fv); ov = sigf(ov); gg = tanh_fast(gg);
                size_t idx = (size_t)b * HID + j;
                float cn = fv * c[idx] + iv * gg;
                c[idx] = cn;
                float hn = ov * tanh_fast(cn);
                if (last) {
                    h[idx] = f2b(hn);
                } else {
                    Xn[(size_t)b * KTOT + j] = f2b(hn * b2f(gbuf[idx]));
                }
            }
        }
    }
}

// ---------------- final kernels (atomic-free) ----------------
__global__ __launch_bounds__(256) void finalY(const u16* __restrict__ h, const float* __restrict__ out_W,
                                              const float* __restrict__ out_b, const float* __restrict__ labels,
                                              const float* __restrict__ is_train, float* __restrict__ preds,
                                              float* __restrict__ bce_part, float* __restrict__ it_part) {
    __shared__ float wbuf[8];
    int tid = threadIdx.x;
    int wave = tid >> 6, lane = tid & 63;
    int cl = lane & 15, quad = lane >> 4;
    int b = blockIdx.x * 16 + wave * 4 + quad;
    const u16x8* hp = (const u16x8*)(h + (size_t)b * HID + cl * 64);
    const float4* wp = (const float4*)(out_W + cl * 64);
    float s = 0.f;
    #pragma unroll
    for (int i = 0; i < 8; ++i) {
        u16x8 hv = hp[i];
        float4 wa = wp[2 * i], wb = wp[2 * i + 1];
        s += b2f(hv[0]) * wa.x + b2f(hv[1]) * wa.y + b2f(hv[2]) * wa.z + b2f(hv[3]) * wa.w
           + b2f(hv[4]) * wb.x + b2f(hv[5]) * wb.y + b2f(hv[6]) * wb.z + b2f(hv[7]) * wb.w;
    }
    s += __shfl_down(s, 8, 16);
    s += __shfl_down(s, 4, 16);
    s += __shfl_down(s, 2, 16);
    s += __shfl_down(s, 1, 16);
    float v1 = 0.f, v2 = 0.f;
    if (cl == 0) {
        float y = s + out_b[0];
        preds[b] = 1.f / (1.f + expf(-y));
        float lab = labels[b], it = is_train[b];
        float mv = fmaxf(-y, 0.f);
        float bce = y - y * lab + mv + logf(expf(-mv) + expf(-y - mv));
        v1 = bce * it; v2 = it;
    }
    v1 += __shfl_xor(v1, 16); v2 += __shfl_xor(v2, 16);
    v1 += __shfl_xor(v1, 32); v2 += __shfl_xor(v2, 32);
    if (lane == 0) { wbuf[wave] = v1; wbuf[4 + wave] = v2; }
    __syncthreads();
    if (tid == 0) {
        bce_part[blockIdx.x] = wbuf[0] + wbuf[1] + wbuf[2] + wbuf[3];
        it_part[blockIdx.x]  = wbuf[4] + wbuf[5] + wbuf[6] + wbuf[7];
    }
}

__global__ __launch_bounds__(256) void finalZ(const float* __restrict__ xnum, const float* __restrict__ xden,
                                              const float* __restrict__ bce_part, const float* __restrict__ it_part,
                                              float* __restrict__ out0) {
    __shared__ float wbuf[12];
    int tid = threadIdx.x, wave = tid >> 6, lane = tid & 63;
    float bs = bce_part[tid], is = it_part[tid];
    #pragma unroll
    for (int off = 32; off; off >>= 1) { bs += __shfl_down(bs, off); is += __shfl_down(is, off); }
    float xl = 0.f;
    for (int t = wave; t < TLEN; t += 4) {
        float n = 0.f, d = 0.f;
        #pragma unroll
        for (int i = 0; i < 4; ++i) { n += xnum[t * 256 + lane + i * 64]; d += xden[t * 256 + lane + i * 64]; }
        #pragma unroll
        for (int off = 32; off; off >>= 1) { n += __shfl_down(n, off); d += __shfl_down(d, off); }
        if (lane == 0) xl += n / (d + 1e-5f);
    }
    if (lane == 0) { wbuf[wave] = xl; wbuf[4 + wave] = bs; wbuf[8 + wave] = is; }
    __syncthreads();
    if (tid == 0) {
        float XL = wbuf[0] + wbuf[1] + wbuf[2] + wbuf[3];
        float BS = wbuf[4] + wbuf[5] + wbuf[6] + wbuf[7];
        float IS = wbuf[8] + wbuf[9] + wbuf[10] + wbuf[11];
        out0[0] = 0.3f * XL + BS / (IS + 1e-5f);
    }
}

// ---------------- launch ----------------
extern "C" void kernel_launch(void* const* d_in, const int* in_sizes, int n_in,
                              void* d_out, int out_size, void* d_ws, size_t ws_size,
                              hipStream_t stream) {
    const float* values   = (const float*)d_in[0];
    const float* masks    = (const float*)d_in[1];
    const float* deltas   = (const float*)d_in[2];
    const float* labels   = (const float*)d_in[3];
    const float* is_train = (const float*)d_in[4];
    const float* td_W     = (const float*)d_in[5];
    const float* td_b     = (const float*)d_in[6];
    const float* W_ih     = (const float*)d_in[7];
    const float* W_hh     = (const float*)d_in[8];
    const float* b_ih     = (const float*)d_in[9];
    const float* b_hh     = (const float*)d_in[10];
    const float* reg_W    = (const float*)d_in[11];
    const float* reg_b    = (const float*)d_in[12];
    const float* out_W    = (const float*)d_in[13];
    const float* out_b    = (const float*)d_in[14];

    float* out = (float*)d_out;
    float* ws_f = (float*)d_ws;

    // workspace: c f32[BH] | h bf16[BH] | Xa bf16[B*KTOT] | Xb bf16[B*KTOT] | W bf16[H4*KTOT]
    //            | gbuf bf16[BH] | bias f32[H4] | tdWtb bf16[64K] | regWb bf16[48K]
    //            | xnum[48*256] | xden[48*256] | bce[256] | it[256]
    float* c      = ws_f;
    u16*   h      = (u16*)(c + BH);
    u16*   Xa     = h + BH;
    u16*   Xb     = Xa + (size_t)BDIM * KTOT;
    u16*   W      = Xb + (size_t)BDIM * KTOT;
    u16*   gbuf   = W + (size_t)H4 * KTOT;
    float* bias_r = (float*)(gbuf + BH);
    u16*   tdWtb  = (u16*)(bias_r + H4);
    u16*   regWb  = tdWtb + 1024 * 64;
    float* xnum_part = (float*)(regWb + 48 * 1024);
    float* xden_part = xnum_part + TLEN * 256;
    float* bce_part  = xden_part + TLEN * 256;
    float* it_part   = bce_part + 256;

    hipMemsetAsync(c, 0, BH * sizeof(float), stream);            // c = 0
    hipMemsetAsync(Xa, 0, (size_t)BDIM * KTOT * sizeof(u16), stream);  // X_hdec(0) = 0

    prep_w<<<H4, 256, 0, stream>>>(W_hh, W_ih, W);
    prep_bias<<<H4 / 256, 256, 0, stream>>>(b_ih, b_hh, bias_r);
    prep_tdwtb<<<256, 256, 0, stream>>>(td_W, tdWtb);
    prep_regwb<<<192, 256, 0, stream>>>(reg_W, regWb);

    float* imput = out + 1 + BDIM;
    for (int t = 0; t < TLEN; t++) {
        u16* cur = (t & 1) ? Xb : Xa;
        u16* nxt = (t & 1) ? Xa : Xb;
        stepR<<<BDIM / 16, 256, 0, stream>>>(values, masks, deltas, tdWtb, td_b, regWb, reg_b,
                                             cur, gbuf, imput, xnum_part, xden_part, t, t < TLEN - 1);
        stepB<<<1024, 256, 0, stream>>>(cur, W, bias_r, gbuf, c, nxt, h, t == TLEN - 1);
    }
    finalY<<<BDIM / 16, 256, 0, stream>>>(h, out_W, out_b, labels, is_train, out + 1, bce_part, it_part);
    finalZ<<<1, 256, 0, stream>>>(xnum_part, xden_part, bce_part, it_part, out);
}

// Round 6
// 3401.930 us; speedup vs baseline: 1.2063x; 1.2063x over previous
//
#include <hip/hip_runtime.h>
#include <math.h>

// Problem constants
#define BDIM 4096
#define TLEN 48
#define FEAT 35
#define HID 1024
#define H4 4096
#define KTOT 1152      // 1024 (hh) + 128 (ih, 70 real + 58 zero pad)
#define KIH2 128

#define BH ((size_t)BDIM * HID)

typedef unsigned short u16;
typedef __bf16 bf16x8 __attribute__((ext_vector_type(8)));
typedef float f32x4 __attribute__((ext_vector_type(4)));
typedef u16 u16x8 __attribute__((ext_vector_type(8)));

__device__ __forceinline__ float b2f(u16 u) {
    union { float f; unsigned i; } v; v.i = ((unsigned)u) << 16; return v.f;
}
__device__ __forceinline__ u16 f2b(float f) {
    union { float f; unsigned i; } v; v.f = f;
    unsigned r = v.i + 0x7FFF + ((v.i >> 16) & 1);
    return (u16)(r >> 16);
}
__device__ __forceinline__ float sigf(float x) { return __builtin_amdgcn_rcpf(1.f + __expf(-x)); }
__device__ __forceinline__ float tanh_fast(float x) { return 1.f - 2.f * __builtin_amdgcn_rcpf(1.f + __expf(2.f * x)); }

// ---------------- prep kernels ----------------
// Combined bf16 weight matrix W[4096][1152], rows reordered:
// orig n = g*HID + j  ->  new n = (j>>5)*128 + g*32 + (j&31)
__global__ __launch_bounds__(256) void prep_w(const float* __restrict__ W_hh, const float* __restrict__ W_ih,
                                              u16* __restrict__ W) {
    int newn = blockIdx.x;
    int nbk = newn >> 7, rem = newn & 127, g = rem >> 5, jl = rem & 31;
    int orig = g * HID + nbk * 32 + jl;
    u16* dst = W + (size_t)newn * KTOT;
    const float* src = W_hh + (size_t)orig * HID;
    #pragma unroll
    for (int it = 0; it < 4; ++it) { int k = it * 256 + threadIdx.x; dst[k] = f2b(src[k]); }
    int k2 = threadIdx.x;
    if (k2 < KIH2) dst[HID + k2] = (k2 < 2 * FEAT) ? f2b(W_ih[(size_t)orig * (2 * FEAT) + k2]) : (u16)0;
}

__global__ __launch_bounds__(256) void prep_bias(const float* __restrict__ b_ih, const float* __restrict__ b_hh,
                                                 float* __restrict__ bias_r) {
    int newn = blockIdx.x * 256 + threadIdx.x;
    int nbk = newn >> 7, rem = newn & 127, g = rem >> 5, jl = rem & 31;
    int orig = g * HID + nbk * 32 + jl;
    bias_r[newn] = b_ih[orig] + b_hh[orig];
}

// tdWtb[j][f] bf16, [1024][64], f>=35 zero.  td_W is [HID][FEAT] row-major already.
__global__ __launch_bounds__(256) void prep_tdwtb(const float* __restrict__ td_W, u16* __restrict__ tdWtb) {
    int idx = blockIdx.x * 256 + threadIdx.x;   // 1024*64 = 256*256
    int row = idx >> 6, f = idx & 63;
    tdWtb[idx] = (f < FEAT) ? f2b(td_W[(size_t)row * FEAT + f]) : (u16)0;
}

// regWb[f][k] bf16, [48][1024], f>=35 zero.  reg_W is [FEAT][HID] row-major.
__global__ __launch_bounds__(256) void prep_regwb(const float* __restrict__ reg_W, u16* __restrict__ regWb) {
    int idx = blockIdx.x * 256 + threadIdx.x;   // 48*1024 = 192*256
    int row = idx >> 10, col = idx & 1023;
    regWb[idx] = (row < FEAT) ? f2b(reg_W[(size_t)row * HID + col]) : (u16)0;
}

// ---------------- stepR: regression + x_c + loss + gamma(t+1) ----------------
__global__ __launch_bounds__(256) void stepR(const float* __restrict__ values, const float* __restrict__ masks,
                                             const float* __restrict__ deltas, const u16* __restrict__ tdWtb,
                                             const float* __restrict__ td_b, const u16* __restrict__ regWb,
                                             const float* __restrict__ reg_b, u16* __restrict__ X,
                                             u16* __restrict__ gbuf, float* __restrict__ imput,
                                             float* __restrict__ xnum_part, float* __restrict__ xden_part,
                                             int t, int gflag) {
    __shared__ u16 d_sh[16 * 64];          // bf16 d(t+1), 16B-chunk XOR swizzled per row
    __shared__ float x_sh[16 * 35], m_sh[16 * 35];
    __shared__ float xhp[4][16][49];       // per-wave regression partials (padded)
    __shared__ float redbuf[8];

    int tid = threadIdx.x;
    int wave = tid >> 6, lane = tid & 63;
    int cl = lane & 15, quad = lane >> 4;
    int b0 = blockIdx.x * 16;

    for (int i = tid; i < 16 * 35; i += 256) {
        int b = i / 35, f = i - b * 35;
        size_t g = ((size_t)(b0 + b) * TLEN + t) * FEAT + f;
        x_sh[i] = values[g];
        m_sh[i] = masks[g];
    }
    if (gflag && tid < 128) {
        int b = tid >> 3, cch = tid & 7;
        const float* drow = deltas + ((size_t)(b0 + b) * TLEN + (t + 1)) * FEAT;
        u16x8 tv;
        #pragma unroll
        for (int k = 0; k < 8; ++k) {
            int f = cch * 8 + k;
            tv[k] = (f < FEAT) ? f2b(drow[f]) : (u16)0;
        }
        int csw = cch ^ (b & 7);
        *(u16x8*)(d_sh + b * 64 + csw * 8) = tv;
    }
    __syncthreads();

    // ---- regression MFMA (K split: wave covers K [wave*256, wave*256+256)) ----
    f32x4 racc[3];
    #pragma unroll
    for (int nt = 0; nt < 3; ++nt) racc[nt] = (f32x4){0.f, 0.f, 0.f, 0.f};
    const u16* xrow = X + (size_t)(b0 + cl) * KTOT + wave * 256;
    #pragma unroll
    for (int ks = 0; ks < 8; ++ks) {
        bf16x8 av = *(const bf16x8*)(xrow + ks * 32 + quad * 8);
        #pragma unroll
        for (int nt = 0; nt < 3; ++nt) {
            bf16x8 bv = *(const bf16x8*)(regWb + (size_t)(nt * 16 + cl) * 1024 + wave * 256 + ks * 32 + quad * 8);
            racc[nt] = __builtin_amdgcn_mfma_f32_16x16x32_bf16(av, bv, racc[nt], 0, 0, 0);
        }
    }
    #pragma unroll
    for (int nt = 0; nt < 3; ++nt)
        #pragma unroll
        for (int r = 0; r < 4; ++r)
            xhp[wave][quad * 4 + r][nt * 16 + cl] = racc[nt][r];

    // ---- gamma MFMA: wave covers j-tiles [wave*16, wave*16+16) ----
    if (gflag) {
        int swc0 = quad ^ (cl & 7);
        int swc1 = (4 + quad) ^ (cl & 7);
        bf16x8 a0 = *(const bf16x8*)(d_sh + cl * 64 + swc0 * 8);
        bf16x8 a1 = *(const bf16x8*)(d_sh + cl * 64 + swc1 * 8);
        #pragma unroll 4
        for (int jt2 = 0; jt2 < 16; ++jt2) {
            int jt = wave * 16 + jt2;
            const u16* tw = tdWtb + (size_t)(jt * 16 + cl) * 64;
            bf16x8 b0v = *(const bf16x8*)(tw + quad * 8);
            bf16x8 b1v = *(const bf16x8*)(tw + 32 + quad * 8);
            f32x4 g4 = (f32x4){0.f, 0.f, 0.f, 0.f};
            g4 = __builtin_amdgcn_mfma_f32_16x16x32_bf16(a0, b0v, g4, 0, 0, 0);
            g4 = __builtin_amdgcn_mfma_f32_16x16x32_bf16(a1, b1v, g4, 0, 0, 0);
            float4 tb = *(const float4*)(td_b + jt * 16 + quad * 4);
            float tbv[4] = {tb.x, tb.y, tb.z, tb.w};
            #pragma unroll
            for (int r = 0; r < 4; ++r) {
                u16 gam = f2b(__expf(-fmaxf(g4[r] + tbv[r], 0.f)));
                gbuf[(size_t)(b0 + quad * 4 + r) * HID + jt * 16 + cl] = gam;
            }
        }
    }
    __syncthreads();

    // ---- epilogue: x_c, imputations, X tail, loss partials ----
    float lossN = 0.f, lossD = 0.f;
    for (int i = tid; i < 16 * 35; i += 256) {
        int b = i / 35, f = i - b * 35;
        float xh = xhp[0][b][f] + xhp[1][b][f] + xhp[2][b][f] + xhp[3][b][f] + reg_b[f];
        float xv = x_sh[i], mv = m_sh[i];
        float xc = mv * xv + (1.f - mv) * xh;
        imput[((size_t)(b0 + b) * TLEN + t) * FEAT + f] = xc;
        u16* Xr = X + (size_t)(b0 + b) * KTOT;
        Xr[HID + f] = f2b(xc);
        Xr[HID + FEAT + f] = f2b(mv);
        lossN += fabsf(xv - xh) * mv;
        lossD += mv;
    }
    for (int i = tid; i < 16 * 58; i += 256) {
        int b = i / 58, k = i - b * 58;
        X[(size_t)(b0 + b) * KTOT + HID + 2 * FEAT + k] = 0;
    }
    #pragma unroll
    for (int off = 32; off; off >>= 1) {
        lossN += __shfl_down(lossN, off);
        lossD += __shfl_down(lossD, off);
    }
    if (lane == 0) { redbuf[wave] = lossN; redbuf[4 + wave] = lossD; }
    __syncthreads();
    if (tid == 0) {
        xnum_part[t * 256 + blockIdx.x] = redbuf[0] + redbuf[1] + redbuf[2] + redbuf[3];
        xden_part[t * 256 + blockIdx.x] = redbuf[4] + redbuf[5] + redbuf[6] + redbuf[7];
    }
}

// ---------------- stepB: bf16 MFMA gates GEMM + fused LSTM cell + decay for t+1 ----------------
// Block tile 256M x 128N, 4 waves; wave = 64M x 128N (acc 4x8 f32x4 = 128 VGPRs).
// Grid 512 blocks (16 mb x 32 nb), XCD decode: xcd=lid&7 owns 4 nb values.
// LDS: As[256x64] 32KB + Bs[128x64] 16KB = 48KB, 16B-chunk XOR swizzle (conflict-free b128).
__global__ __launch_bounds__(256, 2) void stepB(const u16* __restrict__ X, const u16* __restrict__ W,
                                                const float* __restrict__ bias_r, const u16* __restrict__ gbuf,
                                                u16* __restrict__ c, u16* __restrict__ Xn,
                                                u16* __restrict__ h, int last) {
    __shared__ u16 As[256 * 64];
    __shared__ u16 Bs[128 * 64];
    int lid = blockIdx.x;
    int nb = (lid & 7) * 4 + ((lid >> 3) & 3);   // [0,32)
    int mb = lid >> 5;                            // [0,16)
    int tid = threadIdx.x;
    int wave = tid >> 6, lane = tid & 63;
    int lrow = lane >> 3;            // 0..7 row within 8-row staging group
    int gchunk = (lane & 7) ^ lrow;  // swizzled global 16B-chunk to fetch
    int cl = lane & 15, quad = lane >> 4;

    f32x4 acc[4][8];
    #pragma unroll
    for (int mi = 0; mi < 4; ++mi)
        #pragma unroll
        for (int ni = 0; ni < 8; ++ni) acc[mi][ni] = (f32x4){0.f, 0.f, 0.f, 0.f};

    for (int kt = 0; kt < KTOT / 64; ++kt) {
        __syncthreads();
        #pragma unroll
        for (int it = 0; it < 8; ++it) {
            int rl = wave * 64 + it * 8;     // A rows [wave*64 .. wave*64+64)
            const u16* ga = X + (size_t)(mb * 256 + rl + lrow) * KTOT + kt * 64 + gchunk * 8;
            __builtin_amdgcn_global_load_lds((const __attribute__((address_space(1))) void*)ga,
                                             (__attribute__((address_space(3))) void*)(As + rl * 64),
                                             16, 0, 0);
        }
        #pragma unroll
        for (int it = 0; it < 4; ++it) {
            int rl = wave * 32 + it * 8;     // B rows [wave*32 .. wave*32+32)
            const u16* gb = W + (size_t)(nb * 128 + rl + lrow) * KTOT + kt * 64 + gchunk * 8;
            __builtin_amdgcn_global_load_lds((const __attribute__((address_space(1))) void*)gb,
                                             (__attribute__((address_space(3))) void*)(Bs + rl * 64),
                                             16, 0, 0);
        }
        __syncthreads();

        #pragma unroll
        for (int s = 0; s < 2; ++s) {
            int cs = (((4 * s + quad) ^ (cl & 7)) << 3);
            bf16x8 av[4];
            #pragma unroll
            for (int mi = 0; mi < 4; ++mi)
                av[mi] = *(const bf16x8*)(As + (wave * 64 + mi * 16 + cl) * 64 + cs);
            bf16x8 bv[8];
            #pragma unroll
            for (int ni = 0; ni < 8; ++ni)
                bv[ni] = *(const bf16x8*)(Bs + (ni * 16 + cl) * 64 + cs);
            #pragma unroll
            for (int ni = 0; ni < 8; ++ni)
                #pragma unroll
                for (int mi = 0; mi < 4; ++mi)
                    acc[mi][ni] = __builtin_amdgcn_mfma_f32_16x16x32_bf16(av[mi], bv[ni], acc[mi][ni], 0, 0, 0);
        }
    }

    // fused LSTM epilogue; for t<47 write X_hdec(t+1) = h*gamma(t+1), for t=47 write h.
    #pragma unroll
    for (int mi = 0; mi < 4; ++mi) {
        #pragma unroll
        for (int r = 0; r < 4; ++r) {
            int b = mb * 256 + wave * 64 + mi * 16 + quad * 4 + r;
            #pragma unroll
            for (int jh = 0; jh < 2; ++jh) {
                int jl = jh * 16 + cl;
                int j = nb * 32 + jl;
                float iv = acc[mi][jh + 0][r] + bias_r[nb * 128 + jl];
                float fv = acc[mi][jh + 2][r] + bias_r[nb * 128 + 32 + jl];
                float gg = acc[mi][jh + 4][r] + bias_r[nb * 128 + 64 + jl];
                float ov = acc[mi][jh + 6][r] + bias_r[nb * 128 + 96 + jl];
                iv = sigf(iv); fv = sigf(fv); ov = sigf(ov); gg = tanh_fast(gg);
                size_t idx = (size_t)b * HID + j;
                float cn = fv * b2f(c[idx]) + iv * gg;
                c[idx] = f2b(cn);
                float hn = ov * tanh_fast(cn);
                if (last) {
                    h[idx] = f2b(hn);
                } else {
                    Xn[(size_t)b * KTOT + j] = f2b(hn * b2f(gbuf[idx]));
                }
            }
        }
    }
}

// ---------------- final kernels (atomic-free) ----------------
__global__ __launch_bounds__(256) void finalY(const u16* __restrict__ h, const float* __restrict__ out_W,
                                              const float* __restrict__ out_b, const float* __restrict__ labels,
                                              const float* __restrict__ is_train, float* __restrict__ preds,
                                              float* __restrict__ bce_part, float* __restrict__ it_part) {
    __shared__ float wbuf[8];
    int tid = threadIdx.x;
    int wave = tid >> 6, lane = tid & 63;
    int cl = lane & 15, quad = lane >> 4;
    int b = blockIdx.x * 16 + wave * 4 + quad;
    const u16x8* hp = (const u16x8*)(h + (size_t)b * HID + cl * 64);
    const float4* wp = (const float4*)(out_W + cl * 64);
    float s = 0.f;
    #pragma unroll
    for (int i = 0; i < 8; ++i) {
        u16x8 hv = hp[i];
        float4 wa = wp[2 * i], wb = wp[2 * i + 1];
        s += b2f(hv[0]) * wa.x + b2f(hv[1]) * wa.y + b2f(hv[2]) * wa.z + b2f(hv[3]) * wa.w
           + b2f(hv[4]) * wb.x + b2f(hv[5]) * wb.y + b2f(hv[6]) * wb.z + b2f(hv[7]) * wb.w;
    }
    s += __shfl_down(s, 8, 16);
    s += __shfl_down(s, 4, 16);
    s += __shfl_down(s, 2, 16);
    s += __shfl_down(s, 1, 16);
    float v1 = 0.f, v2 = 0.f;
    if (cl == 0) {
        float y = s + out_b[0];
        preds[b] = 1.f / (1.f + expf(-y));
        float lab = labels[b], it = is_train[b];
        float mv = fmaxf(-y, 0.f);
        float bce = y - y * lab + mv + logf(expf(-mv) + expf(-y - mv));
        v1 = bce * it; v2 = it;
    }
    v1 += __shfl_xor(v1, 16); v2 += __shfl_xor(v2, 16);
    v1 += __shfl_xor(v1, 32); v2 += __shfl_xor(v2, 32);
    if (lane == 0) { wbuf[wave] = v1; wbuf[4 + wave] = v2; }
    __syncthreads();
    if (tid == 0) {
        bce_part[blockIdx.x] = wbuf[0] + wbuf[1] + wbuf[2] + wbuf[3];
        it_part[blockIdx.x]  = wbuf[4] + wbuf[5] + wbuf[6] + wbuf[7];
    }
}

__global__ __launch_bounds__(256) void finalZ(const float* __restrict__ xnum, const float* __restrict__ xden,
                                              const float* __restrict__ bce_part, const float* __restrict__ it_part,
                                              float* __restrict__ out0) {
    __shared__ float wbuf[12];
    int tid = threadIdx.x, wave = tid >> 6, lane = tid & 63;
    float bs = bce_part[tid], is = it_part[tid];
    #pragma unroll
    for (int off = 32; off; off >>= 1) { bs += __shfl_down(bs, off); is += __shfl_down(is, off); }
    float xl = 0.f;
    for (int t = wave; t < TLEN; t += 4) {
        float n = 0.f, d = 0.f;
        #pragma unroll
        for (int i = 0; i < 4; ++i) { n += xnum[t * 256 + lane + i * 64]; d += xden[t * 256 + lane + i * 64]; }
        #pragma unroll
        for (int off = 32; off; off >>= 1) { n += __shfl_down(n, off); d += __shfl_down(d, off); }
        if (lane == 0) xl += n / (d + 1e-5f);
    }
    if (lane == 0) { wbuf[wave] = xl; wbuf[4 + wave] = bs; wbuf[8 + wave] = is; }
    __syncthreads();
    if (tid == 0) {
        float XL = wbuf[0] + wbuf[1] + wbuf[2] + wbuf[3];
        float BS = wbuf[4] + wbuf[5] + wbuf[6] + wbuf[7];
        float IS = wbuf[8] + wbuf[9] + wbuf[10] + wbuf[11];
        out0[0] = 0.3f * XL + BS / (IS + 1e-5f);
    }
}

// ---------------- launch ----------------
extern "C" void kernel_launch(void* const* d_in, const int* in_sizes, int n_in,
                              void* d_out, int out_size, void* d_ws, size_t ws_size,
                              hipStream_t stream) {
    const float* values   = (const float*)d_in[0];
    const float* masks    = (const float*)d_in[1];
    const float* deltas   = (const float*)d_in[2];
    const float* labels   = (const float*)d_in[3];
    const float* is_train = (const float*)d_in[4];
    const float* td_W     = (const float*)d_in[5];
    const float* td_b     = (const float*)d_in[6];
    const float* W_ih     = (const float*)d_in[7];
    const float* W_hh     = (const float*)d_in[8];
    const float* b_ih     = (const float*)d_in[9];
    const float* b_hh     = (const float*)d_in[10];
    const float* reg_W    = (const float*)d_in[11];
    const float* reg_b    = (const float*)d_in[12];
    const float* out_W    = (const float*)d_in[13];
    const float* out_b    = (const float*)d_in[14];

    float* out = (float*)d_out;

    // workspace: c bf16[BH] | h bf16[BH] | Xa bf16[B*KTOT] | Xb bf16[B*KTOT] | W bf16[H4*KTOT]
    //            | gbuf bf16[BH] | bias f32[H4] | tdWtb bf16[64K] | regWb bf16[48K]
    //            | xnum[48*256] | xden[48*256] | bce[256] | it[256]
    u16*   c      = (u16*)d_ws;
    u16*   h      = c + BH;
    u16*   Xa     = h + BH;
    u16*   Xb     = Xa + (size_t)BDIM * KTOT;
    u16*   W      = Xb + (size_t)BDIM * KTOT;
    u16*   gbuf   = W + (size_t)H4 * KTOT;
    float* bias_r = (float*)(gbuf + BH);
    u16*   tdWtb  = (u16*)(bias_r + H4);
    u16*   regWb  = tdWtb + 1024 * 64;
    float* xnum_part = (float*)(regWb + 48 * 1024);
    float* xden_part = xnum_part + TLEN * 256;
    float* bce_part  = xden_part + TLEN * 256;
    float* it_part   = bce_part + 256;

    hipMemsetAsync(c, 0, BH * sizeof(u16), stream);                    // c = 0
    hipMemsetAsync(Xa, 0, (size_t)BDIM * KTOT * sizeof(u16), stream);  // X_hdec(0) = 0

    prep_w<<<H4, 256, 0, stream>>>(W_hh, W_ih, W);
    prep_bias<<<H4 / 256, 256, 0, stream>>>(b_ih, b_hh, bias_r);
    prep_tdwtb<<<256, 256, 0, stream>>>(td_W, tdWtb);
    prep_regwb<<<192, 256, 0, stream>>>(reg_W, regWb);

    float* imput = out + 1 + BDIM;
    for (int t = 0; t < TLEN; t++) {
        u16* cur = (t & 1) ? Xb : Xa;
        u16* nxt = (t & 1) ? Xa : Xb;
        stepR<<<BDIM / 16, 256, 0, stream>>>(values, masks, deltas, tdWtb, td_b, regWb, reg_b,
                                             cur, gbuf, imput, xnum_part, xden_part, t, t < TLEN - 1);
        stepB<<<512, 256, 0, stream>>>(cur, W, bias_r, gbuf, c, nxt, h, t == TLEN - 1);
    }
    finalY<<<BDIM / 16, 256, 0, stream>>>(h, out_W, out_b, labels, is_train, out + 1, bce_part, it_part);
    finalZ<<<1, 256, 0, stream>>>(xnum_part, xden_part, bce_part, it_part, out);
}

// Round 7
// 2669.413 us; speedup vs baseline: 1.5373x; 1.2744x over previous
//
#include <hip/hip_runtime.h>
#include <math.h>

// Problem constants
#define BDIM 4096
#define TLEN 48
#define FEAT 35
#define HID 1024
#define H4 4096
#define KTOT 1152      // 1024 (hh) + 128 (ih, 70 real + 58 zero pad)

#define BH ((size_t)BDIM * HID)

typedef unsigned short u16;
typedef unsigned char u8;
typedef __bf16 bf16x8 __attribute__((ext_vector_type(8)));
typedef float f32x4 __attribute__((ext_vector_type(4)));
typedef u16 u16x8 __attribute__((ext_vector_type(8)));
typedef int v8i __attribute__((ext_vector_type(8)));
typedef int v4i __attribute__((ext_vector_type(4)));

#define SCALE1 0x7F7F7F7F   // E8M0 scale = 1.0 in every byte

__device__ __forceinline__ float b2f(u16 u) {
    union { float f; unsigned i; } v; v.i = ((unsigned)u) << 16; return v.f;
}
__device__ __forceinline__ u16 f2b(float f) {
    union { float f; unsigned i; } v; v.f = f;
    unsigned r = v.i + 0x7FFF + ((v.i >> 16) & 1);
    return (u16)(r >> 16);
}
__device__ __forceinline__ unsigned pk4_fp8(float a, float b, float c, float d) {
    int lo = __builtin_amdgcn_cvt_pk_fp8_f32(a, b, 0, false);
    int hi = __builtin_amdgcn_cvt_pk_fp8_f32(c, d, lo, true);
    return (unsigned)hi;
}
__device__ __forceinline__ u8 f2e4m3(float f) {
    return (u8)(__builtin_amdgcn_cvt_pk_fp8_f32(f, 0.f, 0, false) & 0xFF);
}
__device__ __forceinline__ float sigf(float x) { return __builtin_amdgcn_rcpf(1.f + __expf(-x)); }
__device__ __forceinline__ float tanh_fast(float x) { return 1.f - 2.f * __builtin_amdgcn_rcpf(1.f + __expf(2.f * x)); }

// ---------------- prep kernels ----------------
// Combined fp8 weight matrix W[4096][1152], rows reordered:
// orig n = g*HID + j  ->  new n = (j>>5)*128 + g*32 + (j&31)
__global__ __launch_bounds__(256) void prep_w(const float* __restrict__ W_hh, const float* __restrict__ W_ih,
                                              u8* __restrict__ W) {
    int newn = blockIdx.x;
    int nbk = newn >> 7, rem = newn & 127, g = rem >> 5, jl = rem & 31;
    int orig = g * HID + nbk * 32 + jl;
    u8* dst = W + (size_t)newn * KTOT;
    const float* src = W_hh + (size_t)orig * HID;
    const float* src2 = W_ih + (size_t)orig * (2 * FEAT);
    for (int k4 = threadIdx.x; k4 < KTOT / 4; k4 += 256) {
        int k = k4 * 4;
        float f0, f1, f2, f3;
        if (k < HID) {
            f0 = src[k]; f1 = src[k + 1]; f2 = src[k + 2]; f3 = src[k + 3];
        } else {
            int q = k - HID;
            f0 = (q     < 2 * FEAT) ? src2[q]     : 0.f;
            f1 = (q + 1 < 2 * FEAT) ? src2[q + 1] : 0.f;
            f2 = (q + 2 < 2 * FEAT) ? src2[q + 2] : 0.f;
            f3 = (q + 3 < 2 * FEAT) ? src2[q + 3] : 0.f;
        }
        *(unsigned*)(dst + k) = pk4_fp8(f0, f1, f2, f3);
    }
}

__global__ __launch_bounds__(256) void prep_bias(const float* __restrict__ b_ih, const float* __restrict__ b_hh,
                                                 float* __restrict__ bias_r) {
    int newn = blockIdx.x * 256 + threadIdx.x;
    int nbk = newn >> 7, rem = newn & 127, g = rem >> 5, jl = rem & 31;
    int orig = g * HID + nbk * 32 + jl;
    bias_r[newn] = b_ih[orig] + b_hh[orig];
}

// tdWtb[j][f] bf16, [1024][64], f>=35 zero.
__global__ __launch_bounds__(256) void prep_tdwtb(const float* __restrict__ td_W, u16* __restrict__ tdWtb) {
    int idx = blockIdx.x * 256 + threadIdx.x;
    int row = idx >> 6, f = idx & 63;
    tdWtb[idx] = (f < FEAT) ? f2b(td_W[(size_t)row * FEAT + f]) : (u16)0;
}

// regW8[f][k] fp8, [48][1024], f>=35 zero.
__global__ __launch_bounds__(256) void prep_regw8(const float* __restrict__ reg_W, u8* __restrict__ regW8) {
    int row = blockIdx.x;           // 48
    int k = threadIdx.x * 4;        // 1024
    float f0 = 0.f, f1 = 0.f, f2 = 0.f, f3 = 0.f;
    if (row < FEAT) {
        const float* s = reg_W + (size_t)row * HID + k;
        f0 = s[0]; f1 = s[1]; f2 = s[2]; f3 = s[3];
    }
    *(unsigned*)(regW8 + (size_t)row * 1024 + k) = pk4_fp8(f0, f1, f2, f3);
}

// ---------------- stepR: regression + x_c + loss + gamma(t+1) ----------------
__global__ __launch_bounds__(256) void stepR(const float* __restrict__ values, const float* __restrict__ masks,
                                             const float* __restrict__ deltas, const u16* __restrict__ tdWtb,
                                             const float* __restrict__ td_b, const u8* __restrict__ regW8,
                                             const float* __restrict__ reg_b, u8* __restrict__ X,
                                             u16* __restrict__ gbuf, float* __restrict__ imput,
                                             float* __restrict__ xnum_part, float* __restrict__ xden_part,
                                             int t, int gflag) {
    __shared__ u16 d_sh[16 * 64];          // bf16 d(t+1), 16B-chunk XOR swizzled per row
    __shared__ float x_sh[16 * 35], m_sh[16 * 35];
    __shared__ float xhp[4][16][49];       // per-wave regression partials (padded)
    __shared__ float redbuf[8];

    int tid = threadIdx.x;
    int wave = tid >> 6, lane = tid & 63;
    int cl = lane & 15, quad = lane >> 4;
    int b0 = blockIdx.x * 16;

    for (int i = tid; i < 16 * 35; i += 256) {
        int b = i / 35, f = i - b * 35;
        size_t g = ((size_t)(b0 + b) * TLEN + t) * FEAT + f;
        x_sh[i] = values[g];
        m_sh[i] = masks[g];
    }
    if (gflag && tid < 128) {
        int b = tid >> 3, cch = tid & 7;
        const float* drow = deltas + ((size_t)(b0 + b) * TLEN + (t + 1)) * FEAT;
        u16x8 tv;
        #pragma unroll
        for (int k = 0; k < 8; ++k) {
            int f = cch * 8 + k;
            tv[k] = (f < FEAT) ? f2b(drow[f]) : (u16)0;
        }
        int csw = cch ^ (b & 7);
        *(u16x8*)(d_sh + b * 64 + csw * 8) = tv;
    }
    __syncthreads();

    // ---- regression via MX-fp8 MFMA (K split: wave covers K [wave*256, +256)) ----
    f32x4 racc[3];
    #pragma unroll
    for (int nt = 0; nt < 3; ++nt) racc[nt] = (f32x4){0.f, 0.f, 0.f, 0.f};
    const u8* xrow = X + (size_t)(b0 + cl) * KTOT + wave * 256;
    #pragma unroll
    for (int it = 0; it < 2; ++it) {
        v8i av = *(const v8i*)(xrow + it * 128 + quad * 32);
        #pragma unroll
        for (int nt = 0; nt < 3; ++nt) {
            v8i bvv = *(const v8i*)(regW8 + (size_t)(nt * 16 + cl) * 1024 + wave * 256 + it * 128 + quad * 32);
            racc[nt] = __builtin_amdgcn_mfma_scale_f32_16x16x128_f8f6f4(
                av, bvv, racc[nt], 0, 0, 0, SCALE1, 0, SCALE1);
        }
    }
    #pragma unroll
    for (int nt = 0; nt < 3; ++nt)
        #pragma unroll
        for (int r = 0; r < 4; ++r)
            xhp[wave][quad * 4 + r][nt * 16 + cl] = racc[nt][r];

    // ---- gamma MFMA (bf16): wave covers j-tiles [wave*16, wave*16+16) ----
    if (gflag) {
        int swc0 = quad ^ (cl & 7);
        int swc1 = (4 + quad) ^ (cl & 7);
        bf16x8 a0 = *(const bf16x8*)(d_sh + cl * 64 + swc0 * 8);
        bf16x8 a1 = *(const bf16x8*)(d_sh + cl * 64 + swc1 * 8);
        #pragma unroll 4
        for (int jt2 = 0; jt2 < 16; ++jt2) {
            int jt = wave * 16 + jt2;
            const u16* tw = tdWtb + (size_t)(jt * 16 + cl) * 64;
            bf16x8 b0v = *(const bf16x8*)(tw + quad * 8);
            bf16x8 b1v = *(const bf16x8*)(tw + 32 + quad * 8);
            f32x4 g4 = (f32x4){0.f, 0.f, 0.f, 0.f};
            g4 = __builtin_amdgcn_mfma_f32_16x16x32_bf16(a0, b0v, g4, 0, 0, 0);
            g4 = __builtin_amdgcn_mfma_f32_16x16x32_bf16(a1, b1v, g4, 0, 0, 0);
            float4 tb = *(const float4*)(td_b + jt * 16 + quad * 4);
            float tbv[4] = {tb.x, tb.y, tb.z, tb.w};
            #pragma unroll
            for (int r = 0; r < 4; ++r) {
                u16 gam = f2b(__expf(-fmaxf(g4[r] + tbv[r], 0.f)));
                gbuf[(size_t)(b0 + quad * 4 + r) * HID + jt * 16 + cl] = gam;
            }
        }
    }
    __syncthreads();

    // ---- epilogue: x_c, imputations, X tail (fp8), loss partials ----
    float lossN = 0.f, lossD = 0.f;
    for (int i = tid; i < 16 * 35; i += 256) {
        int b = i / 35, f = i - b * 35;
        float xh = xhp[0][b][f] + xhp[1][b][f] + xhp[2][b][f] + xhp[3][b][f] + reg_b[f];
        float xv = x_sh[i], mv = m_sh[i];
        float xc = mv * xv + (1.f - mv) * xh;
        imput[((size_t)(b0 + b) * TLEN + t) * FEAT + f] = xc;
        u8* Xr = X + (size_t)(b0 + b) * KTOT;
        Xr[HID + f] = f2e4m3(xc);
        Xr[HID + FEAT + f] = f2e4m3(mv);
        lossN += fabsf(xv - xh) * mv;
        lossD += mv;
    }
    for (int i = tid; i < 16 * 58; i += 256) {
        int b = i / 58, k = i - b * 58;
        X[(size_t)(b0 + b) * KTOT + HID + 2 * FEAT + k] = 0;
    }
    #pragma unroll
    for (int off = 32; off; off >>= 1) {
        lossN += __shfl_down(lossN, off);
        lossD += __shfl_down(lossD, off);
    }
    if (lane == 0) { redbuf[wave] = lossN; redbuf[4 + wave] = lossD; }
    __syncthreads();
    if (tid == 0) {
        xnum_part[t * 256 + blockIdx.x] = redbuf[0] + redbuf[1] + redbuf[2] + redbuf[3];
        xden_part[t * 256 + blockIdx.x] = redbuf[4] + redbuf[5] + redbuf[6] + redbuf[7];
    }
}

// ---------------- stepB: MX-fp8 MFMA gates GEMM + fused LSTM cell + decay for t+1 ----------------
// Block tile 256M x 128N, 4 waves; wave = 64M x 128N. K=128 per kt, 9 kt iterations.
// LDS: As[256x128B] 32KB + Bs[128x128B] 16KB, 16B-chunk XOR swizzle (row&7).
__global__ __launch_bounds__(256, 2) void stepB(const u8* __restrict__ X, const u8* __restrict__ W,
                                                const float* __restrict__ bias_r, const u16* __restrict__ gbuf,
                                                u16* __restrict__ c, u8* __restrict__ Xn,
                                                u16* __restrict__ h, int last) {
    __shared__ u8 As[256 * 128];
    __shared__ u8 Bs[128 * 128];
    int lid = blockIdx.x;
    int nb = (lid & 7) * 4 + ((lid >> 3) & 3);   // [0,32)
    int mb = lid >> 5;                            // [0,16)
    int tid = threadIdx.x;
    int wave = tid >> 6, lane = tid & 63;
    int lrow = lane >> 3;            // 0..7 row within 8-row staging group
    int gchunk = (lane & 7) ^ lrow;  // swizzled global 16B-chunk to fetch
    int cl = lane & 15, quad = lane >> 4;
    int c7 = cl & 7;

    f32x4 acc[4][8];
    #pragma unroll
    for (int mi = 0; mi < 4; ++mi)
        #pragma unroll
        for (int ni = 0; ni < 8; ++ni) acc[mi][ni] = (f32x4){0.f, 0.f, 0.f, 0.f};

    for (int kt = 0; kt < KTOT / 128; ++kt) {     // 9 iterations
        __syncthreads();
        #pragma unroll
        for (int it = 0; it < 8; ++it) {
            int rl = wave * 64 + it * 8;          // A rows [wave*64 .. +64)
            const u8* ga = X + (size_t)(mb * 256 + rl + lrow) * KTOT + kt * 128 + gchunk * 16;
            __builtin_amdgcn_global_load_lds((const __attribute__((address_space(1))) void*)ga,
                                             (__attribute__((address_space(3))) void*)(As + rl * 128),
                                             16, 0, 0);
        }
        #pragma unroll
        for (int it = 0; it < 4; ++it) {
            int rl = wave * 32 + it * 8;          // B rows [wave*32 .. +32)
            const u8* gb = W + (size_t)(nb * 128 + rl + lrow) * KTOT + kt * 128 + gchunk * 16;
            __builtin_amdgcn_global_load_lds((const __attribute__((address_space(1))) void*)gb,
                                             (__attribute__((address_space(3))) void*)(Bs + rl * 128),
                                             16, 0, 0);
        }
        __syncthreads();

        v8i av[4];
        #pragma unroll
        for (int mi = 0; mi < 4; ++mi) {
            const u8* base = As + (wave * 64 + mi * 16 + cl) * 128;
            v4i lo = *(const v4i*)(base + (((2 * quad) ^ c7) << 4));
            v4i hi = *(const v4i*)(base + (((2 * quad + 1) ^ c7) << 4));
            av[mi] = (v8i){lo[0], lo[1], lo[2], lo[3], hi[0], hi[1], hi[2], hi[3]};
        }
        #pragma unroll
        for (int ni = 0; ni < 8; ++ni) {
            const u8* base = Bs + (ni * 16 + cl) * 128;
            v4i lo = *(const v4i*)(base + (((2 * quad) ^ c7) << 4));
            v4i hi = *(const v4i*)(base + (((2 * quad + 1) ^ c7) << 4));
            v8i bvv = (v8i){lo[0], lo[1], lo[2], lo[3], hi[0], hi[1], hi[2], hi[3]};
            #pragma unroll
            for (int mi = 0; mi < 4; ++mi)
                acc[mi][ni] = __builtin_amdgcn_mfma_scale_f32_16x16x128_f8f6f4(
                    av[mi], bvv, acc[mi][ni], 0, 0, 0, SCALE1, 0, SCALE1);
        }
    }

    // fused LSTM epilogue; for t<47 write X_hdec(t+1) = h*gamma(t+1) in fp8, for t=47 write h bf16.
    #pragma unroll
    for (int mi = 0; mi < 4; ++mi) {
        #pragma unroll
        for (int r = 0; r < 4; ++r) {
            int b = mb * 256 + wave * 64 + mi * 16 + quad * 4 + r;
            #pragma unroll
            for (int jh = 0; jh < 2; ++jh) {
                int jl = jh * 16 + cl;
                int j = nb * 32 + jl;
                float iv = acc[mi][jh + 0][r] + bias_r[nb * 128 + jl];
                float fv = acc[mi][jh + 2][r] + bias_r[nb * 128 + 32 + jl];
                float gg = acc[mi][jh + 4][r] + bias_r[nb * 128 + 64 + jl];
                float ov = acc[mi][jh + 6][r] + bias_r[nb * 128 + 96 + jl];
                iv = sigf(iv); fv = sigf(fv); ov = sigf(ov); gg = tanh_fast(gg);
                size_t idx = (size_t)b * HID + j;
                float cn = fv * b2f(c[idx]) + iv * gg;
                c[idx] = f2b(cn);
                float hn = ov * tanh_fast(cn);
                if (last) {
                    h[idx] = f2b(hn);
                } else {
                    Xn[(size_t)b * KTOT + j] = f2e4m3(hn * b2f(gbuf[idx]));
                }
            }
        }
    }
}

// ---------------- final kernels (atomic-free) ----------------
__global__ __launch_bounds__(256) void finalY(const u16* __restrict__ h, const float* __restrict__ out_W,
                                              const float* __restrict__ out_b, const float* __restrict__ labels,
                                              const float* __restrict__ is_train, float* __restrict__ preds,
                                              float* __restrict__ bce_part, float* __restrict__ it_part) {
    __shared__ float wbuf[8];
    int tid = threadIdx.x;
    int wave = tid >> 6, lane = tid & 63;
    int cl = lane & 15, quad = lane >> 4;
    int b = blockIdx.x * 16 + wave * 4 + quad;
    const u16x8* hp = (const u16x8*)(h + (size_t)b * HID + cl * 64);
    const float4* wp = (const float4*)(out_W + cl * 64);
    float s = 0.f;
    #pragma unroll
    for (int i = 0; i < 8; ++i) {
        u16x8 hv = hp[i];
        float4 wa = wp[2 * i], wb = wp[2 * i + 1];
        s += b2f(hv[0]) * wa.x + b2f(hv[1]) * wa.y + b2f(hv[2]) * wa.z + b2f(hv[3]) * wa.w
           + b2f(hv[4]) * wb.x + b2f(hv[5]) * wb.y + b2f(hv[6]) * wb.z + b2f(hv[7]) * wb.w;
    }
    s += __shfl_down(s, 8, 16);
    s += __shfl_down(s, 4, 16);
    s += __shfl_down(s, 2, 16);
    s += __shfl_down(s, 1, 16);
    float v1 = 0.f, v2 = 0.f;
    if (cl == 0) {
        float y = s + out_b[0];
        preds[b] = 1.f / (1.f + expf(-y));
        float lab = labels[b], it = is_train[b];
        float mv = fmaxf(-y, 0.f);
        float bce = y - y * lab + mv + logf(expf(-mv) + expf(-y - mv));
        v1 = bce * it; v2 = it;
    }
    v1 += __shfl_xor(v1, 16); v2 += __shfl_xor(v2, 16);
    v1 += __shfl_xor(v1, 32); v2 += __shfl_xor(v2, 32);
    if (lane == 0) { wbuf[wave] = v1; wbuf[4 + wave] = v2; }
    __syncthreads();
    if (tid == 0) {
        bce_part[blockIdx.x] = wbuf[0] + wbuf[1] + wbuf[2] + wbuf[3];
        it_part[blockIdx.x]  = wbuf[4] + wbuf[5] + wbuf[6] + wbuf[7];
    }
}

__global__ __launch_bounds__(256) void finalZ(const float* __restrict__ xnum, const float* __restrict__ xden,
                                              const float* __restrict__ bce_part, const float* __restrict__ it_part,
                                              float* __restrict__ out0) {
    __shared__ float wbuf[12];
    int tid = threadIdx.x, wave = tid >> 6, lane = tid & 63;
    float bs = bce_part[tid], is = it_part[tid];
    #pragma unroll
    for (int off = 32; off; off >>= 1) { bs += __shfl_down(bs, off); is += __shfl_down(is, off); }
    float xl = 0.f;
    for (int t = wave; t < TLEN; t += 4) {
        float n = 0.f, d = 0.f;
        #pragma unroll
        for (int i = 0; i < 4; ++i) { n += xnum[t * 256 + lane + i * 64]; d += xden[t * 256 + lane + i * 64]; }
        #pragma unroll
        for (int off = 32; off; off >>= 1) { n += __shfl_down(n, off); d += __shfl_down(d, off); }
        if (lane == 0) xl += n / (d + 1e-5f);
    }
    if (lane == 0) { wbuf[wave] = xl; wbuf[4 + wave] = bs; wbuf[8 + wave] = is; }
    __syncthreads();
    if (tid == 0) {
        float XL = wbuf[0] + wbuf[1] + wbuf[2] + wbuf[3];
        float BS = wbuf[4] + wbuf[5] + wbuf[6] + wbuf[7];
        float IS = wbuf[8] + wbuf[9] + wbuf[10] + wbuf[11];
        out0[0] = 0.3f * XL + BS / (IS + 1e-5f);
    }
}

// ---------------- launch ----------------
extern "C" void kernel_launch(void* const* d_in, const int* in_sizes, int n_in,
                              void* d_out, int out_size, void* d_ws, size_t ws_size,
                              hipStream_t stream) {
    const float* values   = (const float*)d_in[0];
    const float* masks    = (const float*)d_in[1];
    const float* deltas   = (const float*)d_in[2];
    const float* labels   = (const float*)d_in[3];
    const float* is_train = (const float*)d_in[4];
    const float* td_W     = (const float*)d_in[5];
    const float* td_b     = (const float*)d_in[6];
    const float* W_ih     = (const float*)d_in[7];
    const float* W_hh     = (const float*)d_in[8];
    const float* b_ih     = (const float*)d_in[9];
    const float* b_hh     = (const float*)d_in[10];
    const float* reg_W    = (const float*)d_in[11];
    const float* reg_b    = (const float*)d_in[12];
    const float* out_W    = (const float*)d_in[13];
    const float* out_b    = (const float*)d_in[14];

    float* out = (float*)d_out;

    // workspace (bytes): c bf16[BH] | h bf16[BH] | gbuf bf16[BH] | Xa u8[B*KTOT] | Xb u8[B*KTOT]
    //                    | W8 u8[H4*KTOT] | bias f32[H4] | tdWtb bf16[64K] | regW8 u8[48*1024] | parts
    u16*   c      = (u16*)d_ws;
    u16*   h      = c + BH;
    u16*   gbuf   = h + BH;
    u8*    Xa     = (u8*)(gbuf + BH);
    u8*    Xb     = Xa + (size_t)BDIM * KTOT;
    u8*    W8     = Xb + (size_t)BDIM * KTOT;
    float* bias_r = (float*)(W8 + (size_t)H4 * KTOT);
    u16*   tdWtb  = (u16*)(bias_r + H4);
    u8*    regW8  = (u8*)(tdWtb + 1024 * 64);
    float* xnum_part = (float*)(regW8 + 48 * 1024);
    float* xden_part = xnum_part + TLEN * 256;
    float* bce_part  = xden_part + TLEN * 256;
    float* it_part   = bce_part + 256;

    hipMemsetAsync(c, 0, BH * sizeof(u16), stream);                 // c = 0
    hipMemsetAsync(Xa, 0, (size_t)BDIM * KTOT, stream);             // X_hdec(0) = 0

    prep_w<<<H4, 256, 0, stream>>>(W_hh, W_ih, W8);
    prep_bias<<<H4 / 256, 256, 0, stream>>>(b_ih, b_hh, bias_r);
    prep_tdwtb<<<256, 256, 0, stream>>>(td_W, tdWtb);
    prep_regw8<<<48, 256, 0, stream>>>(reg_W, regW8);

    float* imput = out + 1 + BDIM;
    for (int t = 0; t < TLEN; t++) {
        u8* cur = (t & 1) ? Xb : Xa;
        u8* nxt = (t & 1) ? Xa : Xb;
        stepR<<<BDIM / 16, 256, 0, stream>>>(values, masks, deltas, tdWtb, td_b, regW8, reg_b,
                                             cur, gbuf, imput, xnum_part, xden_part, t, t < TLEN - 1);
        stepB<<<512, 256, 0, stream>>>(cur, W8, bias_r, gbuf, c, nxt, h, t == TLEN - 1);
    }
    finalY<<<BDIM / 16, 256, 0, stream>>>(h, out_W, out_b, labels, is_train, out + 1, bce_part, it_part);
    finalZ<<<1, 256, 0, stream>>>(xnum_part, xden_part, bce_part, it_part, out);
}